// Round 8
// baseline (137.662 us; speedup 1.0000x reference)
//
#include <hip/hip_runtime.h>
#include <hip/hip_bf16.h>
#include <math.h>

// ---------------- problem constants ----------------
constexpr int BS   = 512;
constexpr int NBS  = 1536;   // BS * NSENT
constexpr int NPOS = 300;    // HIST*H*W
constexpr int LIN  = 5184;   // FM * 9 * 9
constexpr int KSPLIT = 9, KCH = 576;    // 9*576 = 5184

typedef __attribute__((ext_vector_type(8))) short bf16x8;
typedef __attribute__((ext_vector_type(4))) float f32x4;

static __device__ __forceinline__ short f2bf(float f) {
    unsigned u = __float_as_uint(f);
    unsigned r = (u + 0x7FFFu + ((u >> 16) & 1u)) >> 16;
    return (short)r;
}
static __device__ __forceinline__ unsigned pk2(float a, float b) {
    return ((unsigned)(unsigned short)f2bf(a)) | (((unsigned)(unsigned short)f2bf(b)) << 16);
}
static __device__ __forceinline__ float bf2f_lo(unsigned u) { return __uint_as_float(u << 16); }
static __device__ __forceinline__ float bf2f_hi(unsigned u) { return __uint_as_float(u & 0xFFFF0000u); }

// ---------------- workspace layout (float offsets) ----------------
constexpr size_t OFF_RD   = 0;         // 26*768 fp32 (0..24 rowdot, 25 = bv@W2)
constexpr size_t OFF_FL   = 19968;     // 64 (int)
constexpr size_t OFF_DT   = 20032;     // fp32 [1536][64]
constexpr size_t OFF_WCT  = 118336;    // bf16 [768][768] -> 294912 floats
constexpr size_t OFF_PH   = 413248;    // bf16 [64][768]  -> 24576
constexpr size_t OFF_AB   = 437824;    // bf16 [256][5184] -> 663552
constexpr size_t OFF_SK   = 1101376;   // 55296 fp32
constexpr size_t OFF_SV   = 1156672;   // 55296 fp32
constexpr size_t OFF_SWK  = 1211968;   // 55296 fp32
constexpr size_t OFF_SWV  = 1267264;   // 55296 fp32
constexpr size_t OFF_XKH  = 1322560;   // bf16 [1536][768] -> 589824 floats
constexpr size_t OFF_XVH  = 1912384;   // bf16 [1536][768] -> 589824
constexpr size_t OFF_VWH  = 2502208;   // bf16 [1536][768] -> 589824
constexpr size_t OFF_YH   = 3092032;   // bf16 [512][5184] -> 1327104 floats (2654208 shorts!)
constexpr size_t OFF_PART = 4419136;   // fp32 [9][512][256]; end 5598784 (~22.4MB)

// ======== kS: token scores (pure streaming) + prep as extra blocks ===========
// blocks 0..13823 : wave = one (b,s,t) row -> SK, SV
// blocks 13824+   : prep (AB 0..323, PH 324..398, RD 399..476, WCT 477..620, FL 621)
__global__ __launch_bounds__(256) void kS_scores_prep(
    const float* __restrict__ temb, const float* __restrict__ Wks,
    const float* __restrict__ Wvs, const float* __restrict__ conv_w,
    const float* __restrict__ sprite, const float* __restrict__ Wk,
    const float* __restrict__ Wv, const float* __restrict__ bv,
    const float* __restrict__ a1, const float* __restrict__ v1,
    float* __restrict__ SK, float* __restrict__ SV,
    short* __restrict__ AB, short* __restrict__ PH, short* __restrict__ WCT,
    float* __restrict__ RD, int* __restrict__ FL)
{
    __shared__ float tile[64][65];     // 16.6 KB (used by prep; score path unaffected)
    int tid = threadIdx.x, bx = blockIdx.x;

    if (bx < 13824) {
        int wid = tid >> 6, lane = tid & 63;
        size_t r = (size_t)bx * 4 + wid;          // row over 55296
        const float4* row = (const float4*)temb + r * 192;
        const float4* k4 = (const float4*)Wks;
        const float4* v4 = (const float4*)Wvs;
        float pk = 0.f, pv = 0.f;
        #pragma unroll
        for (int i = 0; i < 3; ++i) {
            int d4 = lane + 64 * i;
            float4 x = row[d4];
            float4 wk = k4[d4], wv = v4[d4];
            pk += x.x * wk.x + x.y * wk.y + x.z * wk.z + x.w * wk.w;
            pv += x.x * wv.x + x.y * wv.y + x.z * wv.z + x.w * wv.w;
        }
        #pragma unroll
        for (int off = 32; off; off >>= 1) {
            pk += __shfl_down(pk, off);
            pv += __shfl_down(pv, off);
        }
        if (lane == 0) { SK[r] = pk; SV[r] = pv; }
        return;
    }

    // ---------------- prep blocks ----------------
    int id = bx - 13824;
    if (id < 324) {
        // AB[n][k]: n<128 -> a1 col n ; n>=128 -> v1 col n-128  (both 5184x128)
        int kt = id % 81, nt = id / 81;
        const float* src = (nt < 2) ? a1 : v1;
        int col0 = (nt & 1) * 64;
        #pragma unroll
        for (int it = 0; it < 16; ++it) {
            int idx = it * 256 + tid; int ki = idx >> 6, ni = idx & 63;
            tile[ki][ni] = src[(size_t)(kt * 64 + ki) * 128 + col0 + ni];
        }
        __syncthreads();
        #pragma unroll
        for (int it = 0; it < 16; ++it) {
            int idx = it * 256 + tid; int ni = idx >> 6, ki = idx & 63;
            AB[(size_t)(nt * 64 + ni) * 5184 + kt * 64 + ki] = f2bf(tile[ki][ni]);
        }
    } else if (id < 399) {
        // PH[o][d] = bf16( sum_c sprite[o][c]*Wk[d][c] ), o<25
        int g = (id - 324) * 256 + tid;
        if (g < 19200) {
            int o = g / 768, d = g - o * 768;
            const float* sp = sprite + o * 256;
            const float* wr = Wk + (size_t)d * 256;
            float s = 0.f;
            for (int c = 0; c < 256; ++c) s += sp[c] * wr[c];
            PH[(size_t)o * 768 + d] = f2bf(s);
        }
    } else if (id < 477) {
        // RD[o][n]: o<25 rowdot rows (sprite), o==25 -> bv@W2
        int g = (id - 399) * 256 + tid;
        if (g < 19968) {
            int o = g / 768, n = g - o * 768;
            int tap = n >> 6, f = n & 63; int t4 = tap / 3, j = tap - t4 * 3;
            const float* sp = (o < 25) ? (sprite + o * 256) : bv;
            float s = 0.f;
            for (int e = 0; e < 256; ++e)
                s += sp[e] * conv_w[(size_t)(t4 * 768 + j * 256 + e) * 64 + f];
            RD[g] = s;
        }
    } else if (id < 621) {
        // WCT[tf][dm] = sum_c W2[tf][c]*Wv[dm][c] (fp32 accum, bf16 out)
        int wid2 = id - 477;
        int bm = (wid2 / 12) * 64, bn = (wid2 % 12) * 64;
        int p = bm >> 6; int t4 = p / 3, jj = p - t4 * 3;
        const float* cwb = conv_w + (size_t)(t4 * 768 + jj * 256) * 64;
        float* As = (float*)tile;          // [32][65]
        float* Bs = (float*)tile + 2080;   // [32][65]
        float acc[4][4];
        #pragma unroll
        for (int i = 0; i < 4; ++i)
            #pragma unroll
            for (int j = 0; j < 4; ++j) acc[i][j] = 0.f;
        int tm = tid >> 4, tn = tid & 15;
        for (int kc = 0; kc < 256; kc += 32) {
            #pragma unroll
            for (int it = 0; it < 8; ++it) {
                int idx = it * 256 + tid; int c = idx >> 6, f = idx & 63;
                As[c * 65 + f] = cwb[(size_t)(kc + c) * 64 + f];
            }
            #pragma unroll
            for (int it = 0; it < 8; ++it) {
                int idx = it * 256 + tid; int d = idx >> 5, c = idx & 31;
                Bs[c * 65 + d] = Wv[(size_t)(bn + d) * 256 + kc + c];
            }
            __syncthreads();
            for (int kk = 0; kk < 32; ++kk) {
                float a[4], b[4];
                #pragma unroll
                for (int i = 0; i < 4; ++i) a[i] = As[kk * 65 + tm * 4 + i];
                #pragma unroll
                for (int j = 0; j < 4; ++j) b[j] = Bs[kk * 65 + tn * 4 + j];
                #pragma unroll
                for (int i = 0; i < 4; ++i)
                    #pragma unroll
                    for (int j = 0; j < 4; ++j) acc[i][j] += a[i] * b[j];
            }
            __syncthreads();
        }
        #pragma unroll
        for (int i = 0; i < 4; ++i)
            #pragma unroll
            for (int j = 0; j < 4; ++j)
                WCT[(size_t)(bm + tm * 4 + i) * 768 + bn + tn * 4 + j] = f2bf(acc[i][j]);
    } else {
        if (tid < 25) {
            float s = 0.f;
            for (int c = 0; c < 256; ++c) s += sprite[tid * 256 + c];
            FL[tid] = (s != 0.0f) ? 1 : 0;
        }
    }
}

// ======== kW: softmax weights over 36 scores (tiny) ==========================
__global__ __launch_bounds__(512) void kW_weights(
    const float* __restrict__ SK, const float* __restrict__ SV,
    float* __restrict__ SWK, float* __restrict__ SWV)
{
    int w = threadIdx.x >> 6, lane = threadIdx.x & 63;
    int bs = blockIdx.x * 8 + w;
    {
        float s = (lane < 36) ? SK[(size_t)bs * 36 + lane] : -1e30f;
        float m = s;
        #pragma unroll
        for (int off = 32; off; off >>= 1) m = fmaxf(m, __shfl_xor(m, off));
        float e = (lane < 36) ? expf(s - m) : 0.f;
        float z = e;
        #pragma unroll
        for (int off = 32; off; off >>= 1) z += __shfl_xor(z, off);
        if (lane < 36) SWK[(size_t)bs * 36 + lane] = e / z;
    }
    {
        float s = (lane < 36) ? SV[(size_t)bs * 36 + lane] : -1e30f;
        float m = s;
        #pragma unroll
        for (int off = 32; off; off >>= 1) m = fmaxf(m, __shfl_xor(m, off));
        float e = (lane < 36) ? expf(s - m) : 0.f;
        float z = e;
        #pragma unroll
        for (int off = 32; off; off >>= 1) z += __shfl_xor(z, off);
        if (lane < 36) SWV[(size_t)bs * 36 + lane] = e / z;
    }
}

// ======== kX: weighted sums (pure streaming, float4, batched prefetch) =======
// block = one (b,s); 192 threads; thread owns 4 d-columns
__global__ __launch_bounds__(192) void kX_sum(
    const float* __restrict__ temb, const float* __restrict__ SWK,
    const float* __restrict__ SWV, short* __restrict__ XKH, short* __restrict__ XVH)
{
    __shared__ float sw[72];
    int tid = threadIdx.x, bs = blockIdx.x;
    if (tid < 36) sw[tid] = SWK[(size_t)bs * 36 + tid];
    else if (tid >= 64 && tid < 100) sw[tid - 28] = SWV[(size_t)bs * 36 + tid - 64];
    __syncthreads();

    const float4* row4 = (const float4*)temb + (size_t)bs * 6912;
    float k0 = 0.f, k1 = 0.f, k2 = 0.f, k3 = 0.f;
    float v0 = 0.f, v1 = 0.f, v2 = 0.f, v3 = 0.f;
    #pragma unroll
    for (int b = 0; b < 3; ++b) {
        float4 xv[12];
        #pragma unroll
        for (int j = 0; j < 12; ++j) xv[j] = row4[(size_t)(b * 12 + j) * 192 + tid];
        #pragma unroll
        for (int j = 0; j < 12; ++j) {
            int t = b * 12 + j;
            float wk = sw[t], wv = sw[36 + t];
            k0 += wk * xv[j].x; k1 += wk * xv[j].y;
            k2 += wk * xv[j].z; k3 += wk * xv[j].w;
            v0 += wv * xv[j].x; v1 += wv * xv[j].y;
            v2 += wv * xv[j].z; v3 += wv * xv[j].w;
        }
    }
    uint2 hk = { pk2(k0, k1), pk2(k2, k3) };
    uint2 hv = { pk2(v0, v1), pk2(v2, v3) };
    ((uint2*)XKH)[(size_t)bs * 192 + tid] = hk;
    ((uint2*)XVH)[(size_t)bs * 192 + tid] = hv;
}

// ---------------- generic MFMA bf16 GEMM: A[M][K] rm, B[N][K] K-major --------
template<int BIAS, int OUTBF>
__global__ __launch_bounds__(256) void gemm_mfma(
    const short* __restrict__ A, const short* __restrict__ B,
    const float* __restrict__ bias, void* __restrict__ Cout,
    int K, int ldc, int klen, size_t czstride)
{
    __shared__ short As[64][40];
    __shared__ short Bs[64][40];
    int tid = threadIdx.x;
    int bm = blockIdx.x * 64, bn = blockIdx.y * 64;
    int wid = tid >> 6, lane = tid & 63;
    int wm = (wid >> 1) * 32, wn = (wid & 1) * 32;
    int l15 = lane & 15, lg = lane >> 4;

    f32x4 zero = {0.f, 0.f, 0.f, 0.f};
    f32x4 acc00 = zero, acc01 = zero, acc10 = zero, acc11 = zero;

    int srow = tid >> 2, kch = (tid & 3) * 8;
    const short* Ap = A + (size_t)(bm + srow) * K + kch + (size_t)blockIdx.z * klen;
    const short* Bp = B + (size_t)(bn + srow) * K + kch + (size_t)blockIdx.z * klen;

    for (int kt = 0; kt < klen; kt += 32) {
        bf16x8 aval = *(const bf16x8*)(Ap + kt);
        bf16x8 bval = *(const bf16x8*)(Bp + kt);
        *(bf16x8*)&As[srow][kch] = aval;
        *(bf16x8*)&Bs[srow][kch] = bval;
        __syncthreads();
        bf16x8 af0 = *(const bf16x8*)&As[wm + l15][lg * 8];
        bf16x8 af1 = *(const bf16x8*)&As[wm + 16 + l15][lg * 8];
        bf16x8 bg0 = *(const bf16x8*)&Bs[wn + l15][lg * 8];
        bf16x8 bg1 = *(const bf16x8*)&Bs[wn + 16 + l15][lg * 8];
        acc00 = __builtin_amdgcn_mfma_f32_16x16x32_bf16(af0, bg0, acc00, 0, 0, 0);
        acc01 = __builtin_amdgcn_mfma_f32_16x16x32_bf16(af0, bg1, acc01, 0, 0, 0);
        acc10 = __builtin_amdgcn_mfma_f32_16x16x32_bf16(af1, bg0, acc10, 0, 0, 0);
        acc11 = __builtin_amdgcn_mfma_f32_16x16x32_bf16(af1, bg1, acc11, 0, 0, 0);
        __syncthreads();
    }

    float* Cf = (float*)Cout + (size_t)blockIdx.z * czstride;
    short* Ch = (short*)Cout;
    #pragma unroll
    for (int i = 0; i < 2; ++i) {
        f32x4 arow0 = (i == 0) ? acc00 : acc10;
        f32x4 arow1 = (i == 0) ? acc01 : acc11;
        #pragma unroll
        for (int j = 0; j < 2; ++j) {
            f32x4 a = (j == 0) ? arow0 : arow1;
            int col = bn + wn + j * 16 + l15;
            float bb = BIAS ? bias[col] : 0.f;
            #pragma unroll
            for (int r = 0; r < 4; ++r) {
                int row = bm + wm + i * 16 + lg * 4 + r;
                float v = a[r] + bb;
                if (OUTBF) Ch[(size_t)row * ldc + col] = f2bf(v);
                else       Cf[(size_t)row * ldc + col] = v;
            }
        }
    }
}

// ======== k3: fused VW gemm (by<12) + DT gemm (by==12), K=768 ================
__global__ __launch_bounds__(256) void k3_vwdt(
    const short* __restrict__ XVH, const short* __restrict__ WCT,
    const float* __restrict__ bvW2, short* __restrict__ VWH,
    const short* __restrict__ XKH, const short* __restrict__ PH,
    float* __restrict__ DT)
{
    __shared__ short As[64][40];
    __shared__ short Bs[64][40];
    int tid = threadIdx.x;
    bool isdt = (blockIdx.y == 12);
    const short* A = isdt ? XKH : XVH;
    const short* B = isdt ? PH  : WCT;
    int bm = blockIdx.x * 64, bn = isdt ? 0 : blockIdx.y * 64;
    int wid = tid >> 6, lane = tid & 63;
    int wm = (wid >> 1) * 32, wn = (wid & 1) * 32;
    int l15 = lane & 15, lg = lane >> 4;

    f32x4 zero = {0.f, 0.f, 0.f, 0.f};
    f32x4 acc00 = zero, acc01 = zero, acc10 = zero, acc11 = zero;

    int srow = tid >> 2, kch = (tid & 3) * 8;
    const short* Ap = A + (size_t)(bm + srow) * 768 + kch;
    const short* Bp = B + (size_t)(bn + srow) * 768 + kch;

    for (int kt = 0; kt < 768; kt += 32) {
        bf16x8 aval = *(const bf16x8*)(Ap + kt);
        bf16x8 bval = *(const bf16x8*)(Bp + kt);
        *(bf16x8*)&As[srow][kch] = aval;
        *(bf16x8*)&Bs[srow][kch] = bval;
        __syncthreads();
        bf16x8 af0 = *(const bf16x8*)&As[wm + l15][lg * 8];
        bf16x8 af1 = *(const bf16x8*)&As[wm + 16 + l15][lg * 8];
        bf16x8 bg0 = *(const bf16x8*)&Bs[wn + l15][lg * 8];
        bf16x8 bg1 = *(const bf16x8*)&Bs[wn + 16 + l15][lg * 8];
        acc00 = __builtin_amdgcn_mfma_f32_16x16x32_bf16(af0, bg0, acc00, 0, 0, 0);
        acc01 = __builtin_amdgcn_mfma_f32_16x16x32_bf16(af0, bg1, acc01, 0, 0, 0);
        acc10 = __builtin_amdgcn_mfma_f32_16x16x32_bf16(af1, bg0, acc10, 0, 0, 0);
        acc11 = __builtin_amdgcn_mfma_f32_16x16x32_bf16(af1, bg1, acc11, 0, 0, 0);
        __syncthreads();
    }

    #pragma unroll
    for (int i = 0; i < 2; ++i) {
        f32x4 arow0 = (i == 0) ? acc00 : acc10;
        f32x4 arow1 = (i == 0) ? acc01 : acc11;
        #pragma unroll
        for (int j = 0; j < 2; ++j) {
            f32x4 a = (j == 0) ? arow0 : arow1;
            int col = bn + wn + j * 16 + l15;
            #pragma unroll
            for (int r = 0; r < 4; ++r) {
                int row = bm + wm + i * 16 + lg * 4 + r;
                if (isdt) DT[(size_t)row * 64 + col] = a[r];
                else      VWH[(size_t)row * 768 + col] = f2bf(a[r] + bvW2[col]);
            }
        }
    }
}

// ======== k4: wts + factored conv + transpose-flatten + lrelu ================
__global__ __launch_bounds__(512) void k4_y(
    const int* __restrict__ state, const float* __restrict__ dt,
    const int* __restrict__ flags, const short* __restrict__ VWH,
    const float* __restrict__ rowdot, const float* __restrict__ conv_b,
    short* __restrict__ y)
{
    int b = blockIdx.x, tid = threadIdx.x;
    __shared__ float s_vW[3 * 768];
    __shared__ float s_w[3][NPOS + 4];
    __shared__ int   s_avt[NPOS + 4];
    __shared__ float s_y[81 * 65];

    const unsigned* vr = (const unsigned*)(VWH + (size_t)b * 3 * 768);
    for (int i = tid; i < 1152; i += 512) {
        unsigned u = vr[i];
        s_vW[2 * i]     = bf2f_lo(u);
        s_vW[2 * i + 1] = bf2f_hi(u);
    }

    for (int code = tid; code < NPOS; code += 512) {
        const int* st = state + ((size_t)b * NPOS + code) * 4;
        int o0 = st[0], o1 = st[1], o2 = st[2], avi = st[3];
        int cnt = flags[o0] + flags[o1] + flags[o2];
        s_avt[code] = avi;
        float w0 = 0.f, w1 = 0.f, w2 = 0.f;
        if (cnt > 0) {
            const float* d0 = dt + (size_t)b * 192;   // [3][64]
            float inv = 1.0f / (16.0f * (float)cnt);
            float q0 = (d0[o0]       + d0[o1]       + d0[o2])       * inv;
            float q1 = (d0[64 + o0]  + d0[64 + o1]  + d0[64 + o2])  * inv;
            float q2 = (d0[128 + o0] + d0[128 + o1] + d0[128 + o2]) * inv;
            float m = fmaxf(q0, fmaxf(q1, q2));
            float e0 = expf(q0 - m), e1 = expf(q1 - m), e2 = expf(q2 - m);
            float is = 1.0f / (6.0f * (e0 + e1 + e2));   // folds att/3 and st/2
            w0 = e0 * is; w1 = e1 * is; w2 = e2 * is;
        }
        s_w[0][code] = w0; s_w[1][code] = w1; s_w[2][code] = w2;
    }
    __syncthreads();

    int f = tid & 63;
    float cb = conv_b[f];
    for (int p = tid >> 6; p < 81; p += 8) {
        int oh = p / 9, ow = p - oh * 9;
        float acc = cb;
        #pragma unroll
        for (int kh = 0; kh < 2; ++kh)
        #pragma unroll
        for (int kw = 0; kw < 2; ++kw) {
            int bc = 3 * ((oh + kh) * 10 + (ow + kw));
            int tbase = ((kh * 2 + kw) * 3) * 64 + f;
            #pragma unroll
            for (int j = 0; j < 3; ++j) {
                int code = bc + j;
                int tf = tbase + j * 64;
                acc += s_w[0][code] * s_vW[tf]
                     + s_w[1][code] * s_vW[768 + tf]
                     + s_w[2][code] * s_vW[2 * 768 + tf];
                acc += 0.5f * rowdot[(size_t)s_avt[code] * 768 + tf];
            }
        }
        acc = acc > 0.f ? acc : 0.01f * acc;
        s_y[p * 65 + f] = acc;
    }
    __syncthreads();
    for (int i = tid; i < LIN; i += 512) {
        int ff = i / 81, pp = i - ff * 81;
        y[(size_t)b * LIN + i] = f2bf(s_y[pp * 65 + ff]);
    }
}

// ======== k6: split-K reduce + layer2 + heads ================================
__global__ __launch_bounds__(128) void k6_heads(
    const float* __restrict__ PART, const float* __restrict__ a1b,
    const float* __restrict__ v1b, const int* __restrict__ action,
    const float* __restrict__ a2, const float* __restrict__ a2b,
    const float* __restrict__ a3, const float* __restrict__ a3b,
    const float* __restrict__ v2, const float* __restrict__ v2b,
    const float* __restrict__ v3, const float* __restrict__ v3b,
    float* __restrict__ out)
{
    int b = blockIdx.x, tid = threadIdx.x;
    __shared__ float h1a[128], h1v[128], h2a[128], red[128];
    __shared__ float lg[5];
    float sa0 = a1b[tid], sv0 = v1b[tid];
    const float* pb = PART + (size_t)b * 256;
    for (int z = 0; z < KSPLIT; ++z) {
        sa0 += pb[(size_t)z * (BS * 256) + tid];
        sv0 += pb[(size_t)z * (BS * 256) + 128 + tid];
    }
    h1a[tid] = sa0 > 0.f ? sa0 : 0.01f * sa0;
    h1v[tid] = sv0 > 0.f ? sv0 : 0.01f * sv0;
    __syncthreads();
    float sa = a2b[tid], sv = v2b[tid];
    for (int k = 0; k < 128; ++k) {
        sa += h1a[k] * a2[k * 128 + tid];
        sv += h1v[k] * v2[k * 128 + tid];
    }
    sa = sa > 0.f ? sa : 0.01f * sa;
    sv = sv > 0.f ? sv : 0.01f * sv;
    h2a[tid] = sa;
    red[tid] = sv * v3[tid];
    __syncthreads();
    for (int s = 64; s > 0; s >>= 1) {
        if (tid < s) red[tid] += red[tid + s];
        __syncthreads();
    }
    if (tid < 5) {
        float l = a3b[tid];
        for (int k = 0; k < 128; ++k) l += h2a[k] * a3[k * 5 + tid];
        lg[tid] = l;
    }
    __syncthreads();
    if (tid == 0) {
        float m = lg[0];
        for (int j2 = 1; j2 < 5; ++j2) m = fmaxf(m, lg[j2]);
        float se = 0.f;
        for (int j2 = 0; j2 < 5; ++j2) se += expf(lg[j2] - m);
        float lse = m + logf(se);
        int act = action[b];
        float ent = 0.f;
        for (int j2 = 0; j2 < 5; ++j2) {
            float lp = lg[j2] - lse;
            ent -= expf(lp) * lp;
        }
        out[b]        = lg[act] - lse;
        out[512 + b]  = red[0] + v3b[0];
        out[1024 + b] = ent;
    }
}

// ---------------- launch ----------------
extern "C" void kernel_launch(void* const* d_in, const int* in_sizes, int n_in,
                              void* d_out, int out_size, void* d_ws, size_t ws_size,
                              hipStream_t stream)
{
    const int*   state  = (const int*)d_in[0];
    const int*   action = (const int*)d_in[1];
    const float* temb   = (const float*)d_in[2];
    const float* sprite = (const float*)d_in[3];
    const float* conv_w = (const float*)d_in[4];
    const float* conv_b = (const float*)d_in[5];
    const float* Wk     = (const float*)d_in[6];
    const float* Wks    = (const float*)d_in[8];
    const float* Wv     = (const float*)d_in[10];
    const float* bv     = (const float*)d_in[11];
    const float* Wvs    = (const float*)d_in[12];
    const float* a1     = (const float*)d_in[14];
    const float* a1b    = (const float*)d_in[15];
    const float* a2     = (const float*)d_in[16];
    const float* a2b    = (const float*)d_in[17];
    const float* a3     = (const float*)d_in[18];
    const float* a3b    = (const float*)d_in[19];
    const float* v1     = (const float*)d_in[20];
    const float* v1b    = (const float*)d_in[21];
    const float* v2     = (const float*)d_in[22];
    const float* v2b    = (const float*)d_in[23];
    const float* v3     = (const float*)d_in[24];
    const float* v3b    = (const float*)d_in[25];
    (void)in_sizes; (void)n_in; (void)out_size; (void)ws_size;

    float* ws  = (float*)d_ws;
    float* RD  = ws + OFF_RD;
    float* bvW2= RD + 25 * 768;
    int*   FL  = (int*)(ws + OFF_FL);
    float* DT  = ws + OFF_DT;
    short* WCT = (short*)(ws + OFF_WCT);
    short* PH  = (short*)(ws + OFF_PH);
    short* AB  = (short*)(ws + OFF_AB);
    float* SK  = ws + OFF_SK;
    float* SV  = ws + OFF_SV;
    float* SWK = ws + OFF_SWK;
    float* SWV = ws + OFF_SWV;
    short* XKH = (short*)(ws + OFF_XKH);
    short* XVH = (short*)(ws + OFF_XVH);
    short* VWH = (short*)(ws + OFF_VWH);
    short* YH  = (short*)(ws + OFF_YH);
    float* PART= ws + OFF_PART;
    float* out = (float*)d_out;

    // 1) pass-1 scores (pure stream) + all prep
    kS_scores_prep<<<13824 + 622, 256, 0, stream>>>(
        temb, Wks, Wvs, conv_w, sprite, Wk, Wv, bv, a1, v1,
        SK, SV, AB, PH, WCT, RD, FL);
    // 2) softmax weights (tiny)
    kW_weights<<<192, 512, 0, stream>>>(SK, SV, SWK, SWV);
    // 3) pass-2 weighted sums (pure stream, L3-assisted)
    kX_sum<<<NBS, 192, 0, stream>>>(temb, SWK, SWV, XKH, XVH);
    // 4) VWH = XVH@WCT^T + bv@W2 (bf16)  ||  DT = XKH@PH^T (fp32)
    k3_vwdt<<<dim3(24,13,1),256,0,stream>>>(XVH, WCT, bvW2, VWH, XKH, PH, DT);
    // 5) conv + flatten
    k4_y<<<BS, 512, 0, stream>>>(state, DT, FL, VWH, RD, conv_b, YH);
    // 6) layer-1 split-K GEMM
    gemm_mfma<0,0><<<dim3(8,4,KSPLIT),256,0,stream>>>(YH, AB, nullptr, PART, 5184, 256, KCH, (size_t)BS*256);
    // 7) reduce + heads
    k6_heads<<<BS, 128, 0, stream>>>(PART, a1b, v1b, action, a2, a2b, a3, a3b,
                                     v2, v2b, v3, v3b, out);
}

// Round 9
// 129.190 us; speedup vs baseline: 1.0656x; 1.0656x over previous
//
#include <hip/hip_runtime.h>
#include <hip/hip_bf16.h>
#include <math.h>

// ---------------- problem constants ----------------
constexpr int BS   = 512;
constexpr int NBS  = 1536;   // BS * NSENT
constexpr int NPOS = 300;    // HIST*H*W
constexpr int LIN  = 5184;   // FM * 9 * 9
constexpr int KSPLIT = 9, KCH = 576;    // 9*576 = 5184

typedef __attribute__((ext_vector_type(8))) short bf16x8;
typedef __attribute__((ext_vector_type(4))) float f32x4;

static __device__ __forceinline__ short f2bf(float f) {
    unsigned u = __float_as_uint(f);
    unsigned r = (u + 0x7FFFu + ((u >> 16) & 1u)) >> 16;
    return (short)r;
}
static __device__ __forceinline__ unsigned pk2(float a, float b) {
    return ((unsigned)(unsigned short)f2bf(a)) | (((unsigned)(unsigned short)f2bf(b)) << 16);
}
static __device__ __forceinline__ float bf2f_lo(unsigned u) { return __uint_as_float(u << 16); }
static __device__ __forceinline__ float bf2f_hi(unsigned u) { return __uint_as_float(u & 0xFFFF0000u); }

// ---------------- workspace layout (float offsets) ----------------
constexpr size_t OFF_RD   = 0;         // 26*768 fp32 (0..24 rowdot, 25 = bv@W2)
constexpr size_t OFF_FL   = 19968;     // 64 (int)
constexpr size_t OFF_DT   = 20032;     // fp32 [1536][64]
constexpr size_t OFF_WCT  = 118336;    // bf16 [768][768] -> 294912 floats
constexpr size_t OFF_PH   = 413248;    // bf16 [64][768]  -> 24576
constexpr size_t OFF_AB   = 437824;    // bf16 [256][5184] -> 663552
constexpr size_t OFF_XKH  = 1101376;   // bf16 [1536][768] -> 589824 floats
constexpr size_t OFF_XVH  = 1691200;   // bf16 [1536][768] -> 589824
constexpr size_t OFF_VWH  = 2281024;   // bf16 [1536][768] -> 589824
constexpr size_t OFF_YH   = 2870848;   // bf16 [512][5184] -> 1327104 floats (2654208 shorts)
constexpr size_t OFF_PART = 4197952;   // fp32 [9][512][256]; end 5377600 (~21.5MB)

#define DOT4(a,b) ((a).x*(b).x + (a).y*(b).y + (a).z*(b).z + (a).w*(b).w)
#define WRED(v) { v += __shfl_down(v,32); v += __shfl_down(v,16); v += __shfl_down(v,8); \
                  v += __shfl_down(v,4);  v += __shfl_down(v,2);  v += __shfl_down(v,1); }

// ======== kT: single-pass temb, register-resident (+ prep as extra blocks) ===
// blocks 0..1535 : (b,s); thread (g=tid/192,c=tid%192) holds 12 tokens x float4
//                  in registers: scores -> softmax -> weighted sums, temb read ONCE
// blocks 1536+   : prep (AB 0..323, PH 324..357, RD 358..392, WCT 393..536, FL 537)
__global__ __launch_bounds__(576) void kT_temb_prep(
    const float* __restrict__ temb, const float* __restrict__ Wks,
    const float* __restrict__ Wvs, const float* __restrict__ conv_w,
    const float* __restrict__ sprite, const float* __restrict__ Wk,
    const float* __restrict__ Wv, const float* __restrict__ bv,
    const float* __restrict__ a1, const float* __restrict__ v1,
    short* __restrict__ XKH, short* __restrict__ XVH,
    short* __restrict__ AB, short* __restrict__ PH, short* __restrict__ WCT,
    float* __restrict__ RD, int* __restrict__ FL)
{
    __shared__ float spart[9][26];   // per-wave partial scores (12 k, 12 v)
    __shared__ float swt[80];        // weights: k at [0..35], v at [40..75]
    __shared__ float big[4608];      // phase-B reduce / prep tiles (18.4 KB)
    int tid = threadIdx.x, bx = blockIdx.x;

    if (bx < NBS) {
        int bs = bx;
        int w = tid >> 6, lane = tid & 63;
        int g = tid / 192, c = tid - g * 192;
        const float4* row4 = (const float4*)temb + (size_t)bs * 6912 + (size_t)g * 2304 + c;

        // ---- one unrolled load burst: 12 float4 into registers ----
        float4 x0  = row4[0];
        float4 x1  = row4[192];
        float4 x2  = row4[384];
        float4 x3  = row4[576];
        float4 x4  = row4[768];
        float4 x5  = row4[960];
        float4 x6  = row4[1152];
        float4 x7  = row4[1344];
        float4 x8  = row4[1536];
        float4 x9  = row4[1728];
        float4 x10 = row4[1920];
        float4 x11 = row4[2112];
        float4 wk = ((const float4*)Wks)[c];
        float4 wv = ((const float4*)Wvs)[c];

        // ---- per-token partial dots ----
        float pk0 = DOT4(x0,wk),  pv0 = DOT4(x0,wv);
        float pk1 = DOT4(x1,wk),  pv1 = DOT4(x1,wv);
        float pk2_ = DOT4(x2,wk), pv2 = DOT4(x2,wv);
        float pk3 = DOT4(x3,wk),  pv3 = DOT4(x3,wv);
        float pk4 = DOT4(x4,wk),  pv4 = DOT4(x4,wv);
        float pk5 = DOT4(x5,wk),  pv5 = DOT4(x5,wv);
        float pk6 = DOT4(x6,wk),  pv6 = DOT4(x6,wv);
        float pk7 = DOT4(x7,wk),  pv7 = DOT4(x7,wv);
        float pk8 = DOT4(x8,wk),  pv8 = DOT4(x8,wv);
        float pk9 = DOT4(x9,wk),  pv9 = DOT4(x9,wv);
        float pk10 = DOT4(x10,wk), pv10 = DOT4(x10,wv);
        float pk11 = DOT4(x11,wk), pv11 = DOT4(x11,wv);

        WRED(pk0)  WRED(pk1)  WRED(pk2_) WRED(pk3)  WRED(pk4)  WRED(pk5)
        WRED(pk6)  WRED(pk7)  WRED(pk8)  WRED(pk9)  WRED(pk10) WRED(pk11)
        WRED(pv0)  WRED(pv1)  WRED(pv2)  WRED(pv3)  WRED(pv4)  WRED(pv5)
        WRED(pv6)  WRED(pv7)  WRED(pv8)  WRED(pv9)  WRED(pv10) WRED(pv11)

        if (lane == 0) {
            spart[w][0] = pk0;   spart[w][1] = pk1;   spart[w][2] = pk2_;
            spart[w][3] = pk3;   spart[w][4] = pk4;   spart[w][5] = pk5;
            spart[w][6] = pk6;   spart[w][7] = pk7;   spart[w][8] = pk8;
            spart[w][9] = pk9;   spart[w][10] = pk10; spart[w][11] = pk11;
            spart[w][12] = pv0;  spart[w][13] = pv1;  spart[w][14] = pv2;
            spart[w][15] = pv3;  spart[w][16] = pv4;  spart[w][17] = pv5;
            spart[w][18] = pv6;  spart[w][19] = pv7;  spart[w][20] = pv8;
            spart[w][21] = pv9;  spart[w][22] = pv10; spart[w][23] = pv11;
        }
        __syncthreads();

        // ---- softmax over 36 tokens (wave 0) ----
        if (w == 0) {
            float sk = -INFINITY, sv = -INFINITY;
            if (lane < 36) {
                int t = lane, gg = t / 12, j = t - gg * 12;
                sk = spart[3*gg][j]    + spart[3*gg+1][j]    + spart[3*gg+2][j];
                sv = spart[3*gg][12+j] + spart[3*gg+1][12+j] + spart[3*gg+2][12+j];
            }
            float mk = sk, mv = sv;
            #pragma unroll
            for (int off = 32; off; off >>= 1) {
                mk = fmaxf(mk, __shfl_xor(mk, off));
                mv = fmaxf(mv, __shfl_xor(mv, off));
            }
            float ek = (lane < 36) ? expf(sk - mk) : 0.f;
            float ev = (lane < 36) ? expf(sv - mv) : 0.f;
            float zk = ek, zv = ev;
            #pragma unroll
            for (int off = 32; off; off >>= 1) {
                zk += __shfl_xor(zk, off);
                zv += __shfl_xor(zv, off);
            }
            if (lane < 36) { swt[lane] = ek / zk; swt[40 + lane] = ev / zv; }
        }
        __syncthreads();

        // ---- weighted sums from registers ----
        float4 ak = {0.f,0.f,0.f,0.f}, av = {0.f,0.f,0.f,0.f};
        int wb = 12 * g;
        #define ACCJ(J, XJ) { float a_ = swt[wb + J], b_ = swt[40 + wb + J]; \
            ak.x += a_*XJ.x; ak.y += a_*XJ.y; ak.z += a_*XJ.z; ak.w += a_*XJ.w; \
            av.x += b_*XJ.x; av.y += b_*XJ.y; av.z += b_*XJ.z; av.w += b_*XJ.w; }
        ACCJ(0,x0) ACCJ(1,x1) ACCJ(2,x2) ACCJ(3,x3) ACCJ(4,x4) ACCJ(5,x5)
        ACCJ(6,x6) ACCJ(7,x7) ACCJ(8,x8) ACCJ(9,x9) ACCJ(10,x10) ACCJ(11,x11)
        #undef ACCJ

        float4* red = (float4*)big;          // [6][192] float4
        red[g * 192 + c] = ak;
        red[576 + g * 192 + c] = av;
        __syncthreads();
        if (tid < 192) {
            float4 a0 = red[tid], a1_ = red[192 + tid], a2 = red[384 + tid];
            float4 b0 = red[576 + tid], b1 = red[768 + tid], b2 = red[960 + tid];
            float kx = a0.x + a1_.x + a2.x, ky = a0.y + a1_.y + a2.y;
            float kz = a0.z + a1_.z + a2.z, kw = a0.w + a1_.w + a2.w;
            float vx = b0.x + b1.x + b2.x, vy = b0.y + b1.y + b2.y;
            float vz = b0.z + b1.z + b2.z, vw = b0.w + b1.w + b2.w;
            uint2 hk = { pk2(kx, ky), pk2(kz, kw) };
            uint2 hv = { pk2(vx, vy), pk2(vz, vw) };
            ((uint2*)XKH)[(size_t)bs * 192 + tid] = hk;
            ((uint2*)XVH)[(size_t)bs * 192 + tid] = hv;
        }
        return;
    }

    // ================= prep blocks (576 threads, stride loops) =================
    int id = bx - NBS;
    if (id < 324) {
        // AB[n][k]: n<128 -> a1 col n ; n>=128 -> v1 col n-128  (both 5184x128)
        float (*tile)[65] = (float(*)[65])big;
        int kt = id % 81, nt = id / 81;
        const float* src = (nt < 2) ? a1 : v1;
        int col0 = (nt & 1) * 64;
        for (int idx = tid; idx < 4096; idx += 576) {
            int ki = idx >> 6, ni = idx & 63;
            tile[ki][ni] = src[(size_t)(kt * 64 + ki) * 128 + col0 + ni];
        }
        __syncthreads();
        for (int idx = tid; idx < 4096; idx += 576) {
            int ni = idx >> 6, ki = idx & 63;
            AB[(size_t)(nt * 64 + ni) * 5184 + kt * 64 + ki] = f2bf(tile[ki][ni]);
        }
    } else if (id < 358) {
        // PH[o][d] = bf16( sum_c sprite[o][c]*Wk[d][c] ), o<25
        int g = (id - 324) * 576 + tid;
        if (g < 19200) {
            int o = g / 768, d = g - o * 768;
            const float* sp = sprite + o * 256;
            const float* wr = Wk + (size_t)d * 256;
            float s = 0.f;
            for (int cc = 0; cc < 256; ++cc) s += sp[cc] * wr[cc];
            PH[(size_t)o * 768 + d] = f2bf(s);
        }
    } else if (id < 393) {
        // RD[o][n]: o<25 rowdot rows (sprite), o==25 -> bv@W2
        int g = (id - 358) * 576 + tid;
        if (g < 19968) {
            int o = g / 768, n = g - o * 768;
            int tap = n >> 6, f = n & 63; int t4 = tap / 3, j = tap - t4 * 3;
            const float* sp = (o < 25) ? (sprite + o * 256) : bv;
            float s = 0.f;
            for (int e = 0; e < 256; ++e)
                s += sp[e] * conv_w[(size_t)(t4 * 768 + j * 256 + e) * 64 + f];
            RD[g] = s;
        }
    } else if (id < 537) {
        // WCT[tf][dm] = sum_c W2[tf][c]*Wv[dm][c] (fp32 accum, bf16 out)
        int wid2 = id - 393;
        int bm = (wid2 / 12) * 64, bn = (wid2 % 12) * 64;
        int p = bm >> 6; int t4 = p / 3, jj = p - t4 * 3;
        const float* cwb = conv_w + (size_t)(t4 * 768 + jj * 256) * 64;
        float* As = big;            // [32][65]
        float* Bs = big + 2080;     // [32][65]
        float acc[4][4];
        #pragma unroll
        for (int i = 0; i < 4; ++i)
            #pragma unroll
            for (int j = 0; j < 4; ++j) acc[i][j] = 0.f;
        int tm = (tid & 255) >> 4, tn = tid & 15;
        for (int kc = 0; kc < 256; kc += 32) {
            for (int idx = tid; idx < 2048; idx += 576) {
                int cc = idx >> 6, f = idx & 63;
                As[cc * 65 + f] = cwb[(size_t)(kc + cc) * 64 + f];
            }
            for (int idx = tid; idx < 2048; idx += 576) {
                int d = idx >> 5, cc = idx & 31;
                Bs[cc * 65 + d] = Wv[(size_t)(bn + d) * 256 + kc + cc];
            }
            __syncthreads();
            if (tid < 256) {
                for (int kk = 0; kk < 32; ++kk) {
                    float a[4], b[4];
                    #pragma unroll
                    for (int i = 0; i < 4; ++i) a[i] = As[kk * 65 + tm * 4 + i];
                    #pragma unroll
                    for (int j = 0; j < 4; ++j) b[j] = Bs[kk * 65 + tn * 4 + j];
                    #pragma unroll
                    for (int i = 0; i < 4; ++i)
                        #pragma unroll
                        for (int j = 0; j < 4; ++j) acc[i][j] += a[i] * b[j];
                }
            }
            __syncthreads();
        }
        if (tid < 256) {
            #pragma unroll
            for (int i = 0; i < 4; ++i)
                #pragma unroll
                for (int j = 0; j < 4; ++j)
                    WCT[(size_t)(bm + tm * 4 + i) * 768 + bn + tn * 4 + j] = f2bf(acc[i][j]);
        }
    } else {
        if (tid < 25) {
            float s = 0.f;
            for (int cc = 0; cc < 256; ++cc) s += sprite[tid * 256 + cc];
            FL[tid] = (s != 0.0f) ? 1 : 0;
        }
    }
}

// ======== k3: fused VW gemm (by<12) + DT gemm (by==12), K=768 ================
__global__ __launch_bounds__(256) void k3_vwdt(
    const short* __restrict__ XVH, const short* __restrict__ WCT,
    const float* __restrict__ bvW2, short* __restrict__ VWH,
    const short* __restrict__ XKH, const short* __restrict__ PH,
    float* __restrict__ DT)
{
    __shared__ short As[64][40];
    __shared__ short Bs[64][40];
    int tid = threadIdx.x;
    bool isdt = (blockIdx.y == 12);
    const short* A = isdt ? XKH : XVH;
    const short* B = isdt ? PH  : WCT;
    int bm = blockIdx.x * 64, bn = isdt ? 0 : blockIdx.y * 64;
    int wid = tid >> 6, lane = tid & 63;
    int wm = (wid >> 1) * 32, wn = (wid & 1) * 32;
    int l15 = lane & 15, lg = lane >> 4;

    f32x4 zero = {0.f, 0.f, 0.f, 0.f};
    f32x4 acc00 = zero, acc01 = zero, acc10 = zero, acc11 = zero;

    int srow = tid >> 2, kch = (tid & 3) * 8;
    const short* Ap = A + (size_t)(bm + srow) * 768 + kch;
    const short* Bp = B + (size_t)(bn + srow) * 768 + kch;

    for (int kt = 0; kt < 768; kt += 32) {
        bf16x8 aval = *(const bf16x8*)(Ap + kt);
        bf16x8 bval = *(const bf16x8*)(Bp + kt);
        *(bf16x8*)&As[srow][kch] = aval;
        *(bf16x8*)&Bs[srow][kch] = bval;
        __syncthreads();
        bf16x8 af0 = *(const bf16x8*)&As[wm + l15][lg * 8];
        bf16x8 af1 = *(const bf16x8*)&As[wm + 16 + l15][lg * 8];
        bf16x8 bg0 = *(const bf16x8*)&Bs[wn + l15][lg * 8];
        bf16x8 bg1 = *(const bf16x8*)&Bs[wn + 16 + l15][lg * 8];
        acc00 = __builtin_amdgcn_mfma_f32_16x16x32_bf16(af0, bg0, acc00, 0, 0, 0);
        acc01 = __builtin_amdgcn_mfma_f32_16x16x32_bf16(af0, bg1, acc01, 0, 0, 0);
        acc10 = __builtin_amdgcn_mfma_f32_16x16x32_bf16(af1, bg0, acc10, 0, 0, 0);
        acc11 = __builtin_amdgcn_mfma_f32_16x16x32_bf16(af1, bg1, acc11, 0, 0, 0);
        __syncthreads();
    }

    #pragma unroll
    for (int i = 0; i < 2; ++i) {
        f32x4 arow0 = (i == 0) ? acc00 : acc10;
        f32x4 arow1 = (i == 0) ? acc01 : acc11;
        #pragma unroll
        for (int j = 0; j < 2; ++j) {
            f32x4 a = (j == 0) ? arow0 : arow1;
            int col = bn + wn + j * 16 + l15;
            #pragma unroll
            for (int r = 0; r < 4; ++r) {
                int row = bm + wm + i * 16 + lg * 4 + r;
                if (isdt) DT[(size_t)row * 64 + col] = a[r];
                else      VWH[(size_t)row * 768 + col] = f2bf(a[r] + bvW2[col]);
            }
        }
    }
}

// ---------------- generic MFMA bf16 GEMM: A[M][K] rm, B[N][K] K-major --------
template<int BIAS, int OUTBF>
__global__ __launch_bounds__(256) void gemm_mfma(
    const short* __restrict__ A, const short* __restrict__ B,
    const float* __restrict__ bias, void* __restrict__ Cout,
    int K, int ldc, int klen, size_t czstride)
{
    __shared__ short As[64][40];
    __shared__ short Bs[64][40];
    int tid = threadIdx.x;
    int bm = blockIdx.x * 64, bn = blockIdx.y * 64;
    int wid = tid >> 6, lane = tid & 63;
    int wm = (wid >> 1) * 32, wn = (wid & 1) * 32;
    int l15 = lane & 15, lg = lane >> 4;

    f32x4 zero = {0.f, 0.f, 0.f, 0.f};
    f32x4 acc00 = zero, acc01 = zero, acc10 = zero, acc11 = zero;

    int srow = tid >> 2, kch = (tid & 3) * 8;
    const short* Ap = A + (size_t)(bm + srow) * K + kch + (size_t)blockIdx.z * klen;
    const short* Bp = B + (size_t)(bn + srow) * K + kch + (size_t)blockIdx.z * klen;

    for (int kt = 0; kt < klen; kt += 32) {
        bf16x8 aval = *(const bf16x8*)(Ap + kt);
        bf16x8 bval = *(const bf16x8*)(Bp + kt);
        *(bf16x8*)&As[srow][kch] = aval;
        *(bf16x8*)&Bs[srow][kch] = bval;
        __syncthreads();
        bf16x8 af0 = *(const bf16x8*)&As[wm + l15][lg * 8];
        bf16x8 af1 = *(const bf16x8*)&As[wm + 16 + l15][lg * 8];
        bf16x8 bg0 = *(const bf16x8*)&Bs[wn + l15][lg * 8];
        bf16x8 bg1 = *(const bf16x8*)&Bs[wn + 16 + l15][lg * 8];
        acc00 = __builtin_amdgcn_mfma_f32_16x16x32_bf16(af0, bg0, acc00, 0, 0, 0);
        acc01 = __builtin_amdgcn_mfma_f32_16x16x32_bf16(af0, bg1, acc01, 0, 0, 0);
        acc10 = __builtin_amdgcn_mfma_f32_16x16x32_bf16(af1, bg0, acc10, 0, 0, 0);
        acc11 = __builtin_amdgcn_mfma_f32_16x16x32_bf16(af1, bg1, acc11, 0, 0, 0);
        __syncthreads();
    }

    float* Cf = (float*)Cout + (size_t)blockIdx.z * czstride;
    short* Ch = (short*)Cout;
    #pragma unroll
    for (int i = 0; i < 2; ++i) {
        f32x4 arow0 = (i == 0) ? acc00 : acc10;
        f32x4 arow1 = (i == 0) ? acc01 : acc11;
        #pragma unroll
        for (int j = 0; j < 2; ++j) {
            f32x4 a = (j == 0) ? arow0 : arow1;
            int col = bn + wn + j * 16 + l15;
            float bb = BIAS ? bias[col] : 0.f;
            #pragma unroll
            for (int r = 0; r < 4; ++r) {
                int row = bm + wm + i * 16 + lg * 4 + r;
                float v = a[r] + bb;
                if (OUTBF) Ch[(size_t)row * ldc + col] = f2bf(v);
                else       Cf[(size_t)row * ldc + col] = v;
            }
        }
    }
}

// ======== k4: wts + factored conv + transpose-flatten + lrelu ================
__global__ __launch_bounds__(512) void k4_y(
    const int* __restrict__ state, const float* __restrict__ dt,
    const int* __restrict__ flags, const short* __restrict__ VWH,
    const float* __restrict__ rowdot, const float* __restrict__ conv_b,
    short* __restrict__ y)
{
    int b = blockIdx.x, tid = threadIdx.x;
    __shared__ float s_vW[3 * 768];
    __shared__ float s_w[3][NPOS + 4];
    __shared__ int   s_avt[NPOS + 4];
    __shared__ float s_y[81 * 65];

    const unsigned* vr = (const unsigned*)(VWH + (size_t)b * 3 * 768);
    for (int i = tid; i < 1152; i += 512) {
        unsigned u = vr[i];
        s_vW[2 * i]     = bf2f_lo(u);
        s_vW[2 * i + 1] = bf2f_hi(u);
    }

    for (int code = tid; code < NPOS; code += 512) {
        const int* st = state + ((size_t)b * NPOS + code) * 4;
        int o0 = st[0], o1 = st[1], o2 = st[2], avi = st[3];
        int cnt = flags[o0] + flags[o1] + flags[o2];
        s_avt[code] = avi;
        float w0 = 0.f, w1 = 0.f, w2 = 0.f;
        if (cnt > 0) {
            const float* d0 = dt + (size_t)b * 192;   // [3][64]
            float inv = 1.0f / (16.0f * (float)cnt);
            float q0 = (d0[o0]       + d0[o1]       + d0[o2])       * inv;
            float q1 = (d0[64 + o0]  + d0[64 + o1]  + d0[64 + o2])  * inv;
            float q2 = (d0[128 + o0] + d0[128 + o1] + d0[128 + o2]) * inv;
            float m = fmaxf(q0, fmaxf(q1, q2));
            float e0 = expf(q0 - m), e1 = expf(q1 - m), e2 = expf(q2 - m);
            float is = 1.0f / (6.0f * (e0 + e1 + e2));   // folds att/3 and st/2
            w0 = e0 * is; w1 = e1 * is; w2 = e2 * is;
        }
        s_w[0][code] = w0; s_w[1][code] = w1; s_w[2][code] = w2;
    }
    __syncthreads();

    int f = tid & 63;
    float cb = conv_b[f];
    for (int p = tid >> 6; p < 81; p += 8) {
        int oh = p / 9, ow = p - oh * 9;
        float acc = cb;
        #pragma unroll
        for (int kh = 0; kh < 2; ++kh)
        #pragma unroll
        for (int kw = 0; kw < 2; ++kw) {
            int bc = 3 * ((oh + kh) * 10 + (ow + kw));
            int tbase = ((kh * 2 + kw) * 3) * 64 + f;
            #pragma unroll
            for (int j = 0; j < 3; ++j) {
                int code = bc + j;
                int tf = tbase + j * 64;
                acc += s_w[0][code] * s_vW[tf]
                     + s_w[1][code] * s_vW[768 + tf]
                     + s_w[2][code] * s_vW[2 * 768 + tf];
                acc += 0.5f * rowdot[(size_t)s_avt[code] * 768 + tf];
            }
        }
        acc = acc > 0.f ? acc : 0.01f * acc;
        s_y[p * 65 + f] = acc;
    }
    __syncthreads();
    for (int i = tid; i < LIN; i += 512) {
        int ff = i / 81, pp = i - ff * 81;
        y[(size_t)b * LIN + i] = f2bf(s_y[pp * 65 + ff]);
    }
}

// ======== k6: split-K reduce + layer2 + heads ================================
__global__ __launch_bounds__(128) void k6_heads(
    const float* __restrict__ PART, const float* __restrict__ a1b,
    const float* __restrict__ v1b, const int* __restrict__ action,
    const float* __restrict__ a2, const float* __restrict__ a2b,
    const float* __restrict__ a3, const float* __restrict__ a3b,
    const float* __restrict__ v2, const float* __restrict__ v2b,
    const float* __restrict__ v3, const float* __restrict__ v3b,
    float* __restrict__ out)
{
    int b = blockIdx.x, tid = threadIdx.x;
    __shared__ float h1a[128], h1v[128], h2a[128], red[128];
    __shared__ float lg[5];
    float sa0 = a1b[tid], sv0 = v1b[tid];
    const float* pb = PART + (size_t)b * 256;
    for (int z = 0; z < KSPLIT; ++z) {
        sa0 += pb[(size_t)z * (BS * 256) + tid];
        sv0 += pb[(size_t)z * (BS * 256) + 128 + tid];
    }
    h1a[tid] = sa0 > 0.f ? sa0 : 0.01f * sa0;
    h1v[tid] = sv0 > 0.f ? sv0 : 0.01f * sv0;
    __syncthreads();
    float sa = a2b[tid], sv = v2b[tid];
    for (int k = 0; k < 128; ++k) {
        sa += h1a[k] * a2[k * 128 + tid];
        sv += h1v[k] * v2[k * 128 + tid];
    }
    sa = sa > 0.f ? sa : 0.01f * sa;
    sv = sv > 0.f ? sv : 0.01f * sv;
    h2a[tid] = sa;
    red[tid] = sv * v3[tid];
    __syncthreads();
    for (int s = 64; s > 0; s >>= 1) {
        if (tid < s) red[tid] += red[tid + s];
        __syncthreads();
    }
    if (tid < 5) {
        float l = a3b[tid];
        for (int k = 0; k < 128; ++k) l += h2a[k] * a3[k * 5 + tid];
        lg[tid] = l;
    }
    __syncthreads();
    if (tid == 0) {
        float m = lg[0];
        for (int j2 = 1; j2 < 5; ++j2) m = fmaxf(m, lg[j2]);
        float se = 0.f;
        for (int j2 = 0; j2 < 5; ++j2) se += expf(lg[j2] - m);
        float lse = m + logf(se);
        int act = action[b];
        float ent = 0.f;
        for (int j2 = 0; j2 < 5; ++j2) {
            float lp = lg[j2] - lse;
            ent -= expf(lp) * lp;
        }
        out[b]        = lg[act] - lse;
        out[512 + b]  = red[0] + v3b[0];
        out[1024 + b] = ent;
    }
}

// ---------------- launch ----------------
extern "C" void kernel_launch(void* const* d_in, const int* in_sizes, int n_in,
                              void* d_out, int out_size, void* d_ws, size_t ws_size,
                              hipStream_t stream)
{
    const int*   state  = (const int*)d_in[0];
    const int*   action = (const int*)d_in[1];
    const float* temb   = (const float*)d_in[2];
    const float* sprite = (const float*)d_in[3];
    const float* conv_w = (const float*)d_in[4];
    const float* conv_b = (const float*)d_in[5];
    const float* Wk     = (const float*)d_in[6];
    const float* Wks    = (const float*)d_in[8];
    const float* Wv     = (const float*)d_in[10];
    const float* bv     = (const float*)d_in[11];
    const float* Wvs    = (const float*)d_in[12];
    const float* a1     = (const float*)d_in[14];
    const float* a1b    = (const float*)d_in[15];
    const float* a2     = (const float*)d_in[16];
    const float* a2b    = (const float*)d_in[17];
    const float* a3     = (const float*)d_in[18];
    const float* a3b    = (const float*)d_in[19];
    const float* v1     = (const float*)d_in[20];
    const float* v1b    = (const float*)d_in[21];
    const float* v2     = (const float*)d_in[22];
    const float* v2b    = (const float*)d_in[23];
    const float* v3     = (const float*)d_in[24];
    const float* v3b    = (const float*)d_in[25];
    (void)in_sizes; (void)n_in; (void)out_size; (void)ws_size;

    float* ws  = (float*)d_ws;
    float* RD  = ws + OFF_RD;
    float* bvW2= RD + 25 * 768;
    int*   FL  = (int*)(ws + OFF_FL);
    float* DT  = ws + OFF_DT;
    short* WCT = (short*)(ws + OFF_WCT);
    short* PH  = (short*)(ws + OFF_PH);
    short* AB  = (short*)(ws + OFF_AB);
    short* XKH = (short*)(ws + OFF_XKH);
    short* XVH = (short*)(ws + OFF_XVH);
    short* VWH = (short*)(ws + OFF_VWH);
    short* YH  = (short*)(ws + OFF_YH);
    float* PART= ws + OFF_PART;
    float* out = (float*)d_out;

    // 1) single-pass temb (register-resident) + all prep
    kT_temb_prep<<<NBS + 538, 576, 0, stream>>>(
        temb, Wks, Wvs, conv_w, sprite, Wk, Wv, bv, a1, v1,
        XKH, XVH, AB, PH, WCT, RD, FL);
    // 2) VWH = XVH@WCT^T + bv@W2 (bf16)  ||  DT = XKH@PH^T (fp32)
    k3_vwdt<<<dim3(24,13,1),256,0,stream>>>(XVH, WCT, bvW2, VWH, XKH, PH, DT);
    // 3) conv + flatten
    k4_y<<<BS, 512, 0, stream>>>(state, DT, FL, VWH, RD, conv_b, YH);
    // 4) layer-1 split-K GEMM
    gemm_mfma<0,0><<<dim3(8,4,KSPLIT),256,0,stream>>>(YH, AB, nullptr, PART, 5184, 256, KCH, (size_t)BS*256);
    // 5) reduce + heads
    k6_heads<<<BS, 128, 0, stream>>>(PART, a1b, v1b, action, a2, a2b, a3, a3b,
                                     v2, v2b, v3, v3b, out);
}